// Round 8
// baseline (182.248 us; speedup 1.0000x reference)
//
#include <hip/hip_runtime.h>
#include <hip/hip_bf16.h>

// CompanyOperationEvaluation R17: BK=128 mega-steps, 160KB LDS, 19 steps.
//  Theory: the ~2200cyc/step invariant across R12-R16 is LDS-pipe
//  throughput x step count (per CU-step ~64 ds_read_b128 ~= 1030cyc).
//  Fix: double the step tile to 128n x 128k (32KB) -> steps 38 -> 19 at the
//  same LDS traffic rate, same waves/CU (8 = 2/SIMD).
//  - 256 blocks x 512 thr x 64 rows, 1 block/CU, exact co-residency.
//  - LDS exactly 163840B: regionA 64KB (feat 64x256 | buf0/1 64x128;
//    x0_sh 64x512 aliases all) + b_sh 3 x 32KB. cw + w2T read from global.
//  - Counted-vmcnt 3-buf pipeline, chunk-XOR swizzle, gld_lds width-16
//    staging (4 instr/thread/stage) -- all carried from R16 verbatim.
//  - L3 reuses L2's wuT tile still in b_sh[0] (zero staging).
// Lesson bank: (R2/R14) MFMA operands from LDS; (R5) >=8 MFMAs/wave/step
// (here 16); (R6) gather issue-early/consume-late; (R13) L2 request rate
// not the limit, block shape at constant TLP neutral; (R15) swizzle alone
// neutral; (R16) counted vmcnt +8%; in-order vmcnt retirement makes
// BAR_VM(4) also drain the early gather loads at L1's first barrier (ok).

typedef __bf16 bf16x8 __attribute__((ext_vector_type(8)));
typedef float floatx4 __attribute__((ext_vector_type(4)));

__device__ __forceinline__ unsigned short f2bf(float x) {
  unsigned int u = __builtin_bit_cast(unsigned int, x);
  u = (u + 0x7FFFu + ((u >> 16) & 1u)) >> 16;
  return (unsigned short)u;
}

// chunk-XOR swizzle: col in shorts; xors the 16B-chunk index (bits 3..5)
// by (row&7). Valid for any sub-chunk offset (low 3 bits preserved).
__device__ __forceinline__ int sz(int row, int col) {
  return col ^ ((row & 7) << 3);
}

#define BAR_VM(N)                                                      \
  do {                                                                 \
    asm volatile("s_waitcnt vmcnt(" #N ") lgkmcnt(0)" ::: "memory");   \
    __builtin_amdgcn_s_barrier();                                      \
    __builtin_amdgcn_sched_barrier(0);                                 \
  } while (0)

// ---------------------------------------------------------------------------
// K1 prep: blocks [0,304) 32x32 transpose tiles; block 304 W2.
// ---------------------------------------------------------------------------
__global__ __launch_bounds__(256) void prep_kernel(
    const float* __restrict__ Wf, const float* __restrict__ Wu,
    const float* __restrict__ W0, const float* __restrict__ W1,
    const float* __restrict__ W2,
    unsigned short* __restrict__ wfT, unsigned short* __restrict__ wuT,
    unsigned short* __restrict__ w0T, unsigned short* __restrict__ w1T,
    unsigned short* __restrict__ w2T) {
  __shared__ unsigned short tile[32][34];
  const int bid = blockIdx.x, tid = threadIdx.x;
  if (bid < 304) {
    int t = bid;
    const float* src; unsigned short* dst; int N, K, kt, nt;
    if (t < 32)       { src = Wf; dst = wfT; N = 128; K = 256; kt = t >> 2;       nt = t & 3; }
    else if (t < 48)  { t -= 32;  src = Wu; dst = wuT; N = 128; K = 128; kt = t >> 2; nt = t & 3; }
    else if (t < 176) { t -= 48;  src = W0; dst = w0T; N = 512; K = 256; kt = t >> 4; nt = t & 15; }
    else              { t -= 176; src = W1; dst = w1T; N = 256; K = 512; kt = t >> 3; nt = t & 7; }
    {
      int r = tid >> 3, cg = (tid & 7) * 4;
      float4 v = *(const float4*)(src + (size_t)(kt * 32 + r) * N + nt * 32 + cg);
      tile[r][cg + 0] = f2bf(v.x); tile[r][cg + 1] = f2bf(v.y);
      tile[r][cg + 2] = f2bf(v.z); tile[r][cg + 3] = f2bf(v.w);
    }
    __syncthreads();
    {
      int rp = tid >> 3, cg = (tid & 7) * 4;
      uint2 o;
      o.x = (unsigned)tile[cg + 0][rp] | ((unsigned)tile[cg + 1][rp] << 16);
      o.y = (unsigned)tile[cg + 2][rp] | ((unsigned)tile[cg + 3][rp] << 16);
      *(uint2*)(dst + (size_t)(nt * 32 + rp) * K + kt * 32 + cg) = o;
    }
  } else {
#pragma unroll
    for (int i = 0; i < 8; ++i) {
      int g = tid * 8 + i, k = g >> 3, n = g & 7;
      w2T[n * 256 + k] = f2bf(W2[g]);
    }
  }
}

// ---------------------------------------------------------------------------
// Staging: one 128x128 B step-tile (32KB) via global_load_lds width=16.
// 2048 chunks of 16B; 4 instr/thread (512 thr). LDS dest linear (chunk*16B);
// global source inverse-swizzled: stored chunk (row,seg) holds logical
// chunk seg^(row&7).
// ---------------------------------------------------------------------------
template <int LDK>
__device__ __forceinline__ void stageB(unsigned short* dstbase,
                                       const unsigned short* __restrict__ src,
                                       int tid) {
#pragma unroll
  for (int i = 0; i < 4; ++i) {
    int chunk = i * 512 + tid;
    int row = chunk >> 4, seg = chunk & 15;
    int segl = seg ^ (row & 7);
    const unsigned short* g = src + (size_t)row * LDK + segl * 8;
    unsigned short* d = dstbase + chunk * 8;
    __builtin_amdgcn_global_load_lds((const unsigned int*)g, (unsigned int*)d,
                                     16, 0, 0);
  }
}

template <int PASS, int LDK>
__device__ __forceinline__ const unsigned short* srcstep(
    const unsigned short* __restrict__ s, int st) {
  return s + (size_t)(st / PASS) * 128 * LDK + (st % PASS) * 128;
}

// One K-step (BK=128): 8 A + 8 B ds_reads, 16 MFMAs (all reads swizzled).
// Wave (wm,wn) covers rows wm*32+[0,32), cols wn*32+[0,32).
template <int LDA>
__device__ __forceinline__ void mstep(const unsigned short* A,
                                      const unsigned short* bt, int k0,
                                      floatx4* acc, int m16, int quad,
                                      int wm, int wn) {
#pragma unroll
  for (int kk = 0; kk < 128; kk += 32) {
    const int ca = k0 + kk + quad * 8;
    const int cb = kk + quad * 8;
    const int ra0 = wm * 32 + m16, ra1 = wm * 32 + 16 + m16;
    const int rb0 = wn * 32 + m16, rb1 = wn * 32 + 16 + m16;
    bf16x8 a0 = *(const bf16x8*)&A[ra0 * LDA + sz(ra0, ca)];
    bf16x8 a1 = *(const bf16x8*)&A[ra1 * LDA + sz(ra1, ca)];
    bf16x8 b0 = *(const bf16x8*)&bt[rb0 * 128 + sz(rb0, cb)];
    bf16x8 b1 = *(const bf16x8*)&bt[rb1 * 128 + sz(rb1, cb)];
    acc[0] = __builtin_amdgcn_mfma_f32_16x16x32_bf16(a0, b0, acc[0], 0, 0, 0);
    acc[1] = __builtin_amdgcn_mfma_f32_16x16x32_bf16(a0, b1, acc[1], 0, 0, 0);
    acc[2] = __builtin_amdgcn_mfma_f32_16x16x32_bf16(a1, b0, acc[2], 0, 0, 0);
    acc[3] = __builtin_amdgcn_mfma_f32_16x16x32_bf16(a1, b1, acc[3], 0, 0, 0);
  }
}

// Pipelined phase, 3-buf, lookahead-2, counted vmcnt (R16 schedule).
template <int T, int LDA, int PASS, int LDK>
__device__ __forceinline__ void gemm_phase(
    const unsigned short* A, const unsigned short* __restrict__ src,
    unsigned short* b_sh, floatx4* acc, int tid, int m16, int quad, int wm,
    int wn) {
  stageB<LDK>(b_sh, srcstep<PASS, LDK>(src, 0), tid);
  if (T > 1) {
    stageB<LDK>(b_sh + 16384, srcstep<PASS, LDK>(src, 1), tid);
    BAR_VM(4);  // stage0 landed; stage1 stays in flight
  } else {
    BAR_VM(0);
  }
#pragma unroll
  for (int t = 0; t < T; ++t) {
    if (t + 2 < T)
      stageB<LDK>(b_sh + ((t + 2) % 3) * 16384, srcstep<PASS, LDK>(src, t + 2),
                  tid);
    mstep<LDA>(A, b_sh + (t % 3) * 16384, (t % PASS) * 128,
               acc + (t / PASS) * 4, m16, quad, wm, wn);
    if (t + 2 < T) {
      BAR_VM(4);  // stage(t+1) landed; stage(t+2) in flight
    } else {
      BAR_VM(0);  // phase tail
    }
  }
}

// ---------------------------------------------------------------------------
// K2 fused_mlp: 256 blocks x 64 rows x 512 threads. LDS = 163840 B exactly.
// ---------------------------------------------------------------------------
__global__ __launch_bounds__(512, 2) void fused_mlp_kernel(
    const float* __restrict__ features, const int* __restrict__ ent_idx,
    const float* __restrict__ head_tab, const float* __restrict__ ent_tab,
    const float* __restrict__ w_cf, const float* __restrict__ w_fc,
    const float* __restrict__ w_ef, const float* __restrict__ w_fe,
    const float* __restrict__ b_c, const float* __restrict__ b_e,
    const unsigned short* __restrict__ wfT,
    const unsigned short* __restrict__ wuT, const float* __restrict__ bf_,
    const float* __restrict__ bu,
    const unsigned short* __restrict__ w0T, const float* __restrict__ b0,
    const unsigned short* __restrict__ w1T, const float* __restrict__ b1,
    const unsigned short* __restrict__ w2T, const float* __restrict__ b2,
    const int* __restrict__ target, float* __restrict__ out) {
  // regionA (shorts): [0,16384) feat/A_sh 64x256; [16384,24576) buf0 64x128;
  // [24576,32768) buf1 64x128. x0_sh 64x512 = 32768 aliases all of regionA.
  __shared__ __align__(16) unsigned short regionA[32768];    // 64 KB
  __shared__ __align__(16) unsigned short b_sh[3 * 16384];   // 96 KB
  unsigned short* feat_sh = regionA;
  unsigned short* buf0 = regionA + 16384;
  unsigned short* buf1 = regionA + 24576;
  unsigned short* A_sh = regionA;   // 64x256: [cf2 | e] concat (swizzled)
  unsigned short* x0_sh = regionA;  // 64x512 (swizzled)
  unsigned short* x1_sh = b_sh;     // 64x264 = 16896 shorts (UNswizzled)

  const int tid = threadIdx.x;
  const int r0 = blockIdx.x * 64;
  const int lane = tid & 63, wave = tid >> 6;
  const int m16 = lane & 15, quad = lane >> 4;
  const int wm = wave >> 2, wn = wave & 3;

  // ---- gather issue (earliest point; consumed after L1) ----
  // 8 lanes/row, 64 rows, 16 fp32/lane per table.
  const int grow = tid >> 3, gpart = tid & 7;
  const int gidx = ent_idx[r0 + grow];
  const float* hp = head_tab + (size_t)gidx * 128 + gpart * 16;
  const float* ep = ent_tab + (size_t)gidx * 128 + gpart * 16;
  float4 h4[4], e4[4];
#pragma unroll
  for (int j = 0; j < 4; ++j) {
    h4[j] = *(const float4*)(hp + j * 4);
    e4[j] = *(const float4*)(ep + j * 4);
  }

  // stage features fp32->bf16 (swizzled writes): 4096 float4, 8/thread
#pragma unroll
  for (int i = 0; i < 8; ++i) {
    int idx4 = i * 512 + tid;
    int row = idx4 >> 6, c = (idx4 & 63) * 4;
    float4 v = *(const float4*)(features + (size_t)(r0 + row) * 256 + c);
    uint2 o;
    o.x = (unsigned)f2bf(v.x) | ((unsigned)f2bf(v.y) << 16);
    o.y = (unsigned)f2bf(v.z) | ((unsigned)f2bf(v.w) << 16);
    *(uint2*)&feat_sh[row * 256 + sz(row, c)] = o;
  }

  floatx4 acc[4];
  // ---- L1: cf0 = relu(feat @ Wf + bf), K=256, N=128, T=2 ----
#pragma unroll
  for (int j = 0; j < 4; ++j) acc[j] = (floatx4){0.f, 0.f, 0.f, 0.f};
  gemm_phase<2, 256, 2, 256>(feat_sh, wfT, b_sh, acc, tid, m16, quad, wm, wn);
#pragma unroll
  for (int mi = 0; mi < 2; ++mi)
#pragma unroll
    for (int ni = 0; ni < 2; ++ni) {
      int col = wn * 32 + ni * 16 + m16;
      float bv = bf_[col];
#pragma unroll
      for (int r = 0; r < 4; ++r) {
        int row = wm * 32 + mi * 16 + quad * 4 + r;
        buf0[row * 128 + sz(row, col)] =
            f2bf(fmaxf(acc[mi * 2 + ni][r] + bv, 0.f));
      }
    }

  // ---- cross_compress x2 (consume gather) -> A_sh[:,128:256] ----
  // feat cols 128:256 dead (L1's final barrier drained all A reads); next
  // reader of A_sh[:,128:256] is x0, behind several barriers. Cross weights
  // read direct from global (8KB total, L2-hot, once per block).
  {
    float h[16], e[16];
#pragma unroll
    for (int j = 0; j < 4; ++j) {
      h[4 * j + 0] = h4[j].x; h[4 * j + 1] = h4[j].y;
      h[4 * j + 2] = h4[j].z; h[4 * j + 3] = h4[j].w;
      e[4 * j + 0] = e4[j].x; e[4 * j + 1] = e4[j].y;
      e[4 * j + 2] = e4[j].z; e[4 * j + 3] = e4[j].w;
    }
    float wcf[16], wfc[16], wef[16], wfe[16];
#pragma unroll
    for (int jj = 0; jj < 4; ++jj) {
      *(float4*)&wcf[jj * 4] = *(const float4*)(w_cf + gpart * 16 + jj * 4);
      *(float4*)&wfc[jj * 4] = *(const float4*)(w_fc + gpart * 16 + jj * 4);
      *(float4*)&wef[jj * 4] = *(const float4*)(w_ef + gpart * 16 + jj * 4);
      *(float4*)&wfe[jj * 4] = *(const float4*)(w_fe + gpart * 16 + jj * 4);
    }
    const float bc = b_c[0], be = b_e[0];
#pragma unroll
    for (int it = 0; it < 2; ++it) {
      float d0 = 0.f, d1 = 0.f, d2 = 0.f, d3 = 0.f;
#pragma unroll
      for (int j = 0; j < 16; ++j) {
        d0 += e[j] * wcf[j]; d1 += h[j] * wfc[j];
        d2 += e[j] * wef[j]; d3 += h[j] * wfe[j];
      }
#pragma unroll
      for (int s = 1; s < 8; s <<= 1) {
        d0 += __shfl_xor(d0, s); d1 += __shfl_xor(d1, s);
        d2 += __shfl_xor(d2, s); d3 += __shfl_xor(d3, s);
      }
#pragma unroll
      for (int j = 0; j < 16; ++j) {
        float nh = h[j] * d0 + e[j] * d1 + bc;
        float ne = h[j] * d2 + e[j] * d3 + be;
        h[j] = nh; e[j] = ne;
      }
    }
    uint4 o0, o1;
    unsigned* w = (unsigned*)&o0;
#pragma unroll
    for (int j = 0; j < 4; ++j)
      w[j] = (unsigned)f2bf(e[2 * j]) | ((unsigned)f2bf(e[2 * j + 1]) << 16);
    w = (unsigned*)&o1;
#pragma unroll
    for (int j = 0; j < 4; ++j)
      w[j] = (unsigned)f2bf(e[8 + 2 * j]) |
             ((unsigned)f2bf(e[8 + 2 * j + 1]) << 16);
    const int c0 = 128 + gpart * 16;
    *(uint4*)&A_sh[grow * 256 + sz(grow, c0)] = o0;
    *(uint4*)&A_sh[grow * 256 + sz(grow, c0 + 8)] = o1;
  }

  // ---- L2: cf1 = relu(cf0 @ Wu + bu), K=128, N=128, T=1 ----
#pragma unroll
  for (int j = 0; j < 4; ++j) acc[j] = (floatx4){0.f, 0.f, 0.f, 0.f};
  gemm_phase<1, 128, 1, 128>(buf0, wuT, b_sh, acc, tid, m16, quad, wm, wn);
#pragma unroll
  for (int mi = 0; mi < 2; ++mi)
#pragma unroll
    for (int ni = 0; ni < 2; ++ni) {
      int col = wn * 32 + ni * 16 + m16;
      float bv = bu[col];
#pragma unroll
      for (int r = 0; r < 4; ++r) {
        int row = wm * 32 + mi * 16 + quad * 4 + r;
        buf1[row * 128 + sz(row, col)] =
            f2bf(fmaxf(acc[mi * 2 + ni][r] + bv, 0.f));
      }
    }

  // ---- L3: cf2 = relu(cf1 @ Wu + bu) -> A_sh[:,0:128] ----
  // b_sh[0] still holds the full wuT tile from L2: zero staging.
#pragma unroll
  for (int j = 0; j < 4; ++j) acc[j] = (floatx4){0.f, 0.f, 0.f, 0.f};
  BAR_VM(0);  // buf1 (L2 epilogue ds_writes) visible to all waves
  mstep<128>(buf1, b_sh, 0, acc, m16, quad, wm, wn);
  BAR_VM(0);  // drain b_sh reads before x0's stage(0) overwrites b_sh
#pragma unroll
  for (int mi = 0; mi < 2; ++mi)
#pragma unroll
    for (int ni = 0; ni < 2; ++ni) {
      int col = wn * 32 + ni * 16 + m16;
      float bv = bu[col];
#pragma unroll
      for (int r = 0; r < 4; ++r) {
        int row = wm * 32 + mi * 16 + quad * 4 + r;
        A_sh[row * 256 + sz(row, col)] =
            f2bf(fmaxf(acc[mi * 2 + ni][r] + bv, 0.f));
      }
    }

  // ---- x0 = relu(A @ W0 + b0), K=256, N=512: 4 n-passes x 2 k = T=8 ----
  floatx4 acc16[16];
#pragma unroll
  for (int j = 0; j < 16; ++j) acc16[j] = (floatx4){0.f, 0.f, 0.f, 0.f};
  gemm_phase<8, 256, 2, 256>(A_sh, w0T, b_sh, acc16, tid, m16, quad, wm, wn);
  // epilogue -> x0_sh (overwrites regionA; all A reads drained at final bar)
#pragma unroll
  for (int np = 0; np < 4; ++np)
#pragma unroll
    for (int mi = 0; mi < 2; ++mi)
#pragma unroll
      for (int ni = 0; ni < 2; ++ni) {
        int col = np * 128 + wn * 32 + ni * 16 + m16;
        float bv = b0[col];
#pragma unroll
        for (int r = 0; r < 4; ++r) {
          int row = wm * 32 + mi * 16 + quad * 4 + r;
          x0_sh[row * 512 + sz(row, col)] =
              f2bf(fmaxf(acc16[np * 4 + mi * 2 + ni][r] + bv, 0.f));
        }
      }

  // ---- x1 = relu(x0 @ W1 + b1), K=512, N=256: 2 n-passes x 4 k = T=8 ----
  // x1's stage(0) safe: x0's final barrier drained all b_sh reads; x1's
  // first barrier flushes the x0_sh epilogue ds_writes.
  floatx4 acc8[8];
#pragma unroll
  for (int j = 0; j < 8; ++j) acc8[j] = (floatx4){0.f, 0.f, 0.f, 0.f};
  gemm_phase<8, 512, 4, 512>(x0_sh, w1T, b_sh, acc8, tid, m16, quad, wm, wn);
  // epilogue -> x1_sh aliased over b_sh (all b_sh reads drained at final bar)
#pragma unroll
  for (int np = 0; np < 2; ++np)
#pragma unroll
    for (int mi = 0; mi < 2; ++mi)
#pragma unroll
      for (int ni = 0; ni < 2; ++ni) {
        int col = np * 128 + wn * 32 + ni * 16 + m16;
        float bv = b1[col];
#pragma unroll
        for (int r = 0; r < 4; ++r)
          x1_sh[(wm * 32 + mi * 16 + quad * 4 + r) * 264 + col] =
              f2bf(fmaxf(acc8[np * 4 + mi * 2 + ni][r] + bv, 0.f));
      }
  BAR_VM(0);

  // W2 GEMV + softmax: 8 lanes/row, 64 rows; w2T direct from global
  // (4KB, L2-hot, tail phase only).
  {
    int row = tid >> 3, q = tid & 7;
    float p[8];
#pragma unroll
    for (int n = 0; n < 8; ++n) p[n] = 0.f;
#pragma unroll
    for (int jb = 0; jb < 4; ++jb) {
      bf16x8 xv = *(const bf16x8*)&x1_sh[row * 264 + q * 32 + jb * 8];
#pragma unroll
      for (int n = 0; n < 8; ++n) {
        bf16x8 wv = *(const bf16x8*)(w2T + n * 256 + q * 32 + jb * 8);
#pragma unroll
        for (int j = 0; j < 8; ++j) p[n] += (float)xv[j] * (float)wv[j];
      }
    }
#pragma unroll
    for (int s = 1; s < 8; s <<= 1)
#pragma unroll
      for (int n = 0; n < 8; ++n) p[n] += __shfl_xor(p[n], s);
    if (q == 0) {
      float mx = -1e30f;
#pragma unroll
      for (int n = 0; n < 8; ++n) {
        p[n] = fmaxf(p[n] + b2[n], 0.f);
        mx = fmaxf(mx, p[n]);
      }
      float sum = 0.f;
#pragma unroll
      for (int n = 0; n < 8; ++n) { p[n] = __expf(p[n] - mx); sum += p[n]; }
      const float inv = 1.f / sum;
      const int gr = r0 + row;
      float4 o0 = {p[0] * inv, p[1] * inv, p[2] * inv, p[3] * inv};
      float4 o1 = {p[4] * inv, p[5] * inv, p[6] * inv, p[7] * inv};
      *(float4*)(out + (size_t)gr * 8) = o0;
      *(float4*)(out + (size_t)gr * 8 + 4) = o1;
      out[16384 * 8 + gr] = (float)target[gr];
    }
  }
}

extern "C" void kernel_launch(void* const* d_in, const int* in_sizes, int n_in,
                              void* d_out, int out_size, void* d_ws, size_t ws_size,
                              hipStream_t stream) {
  const float* features = (const float*)d_in[0];
  const int* ent_idx    = (const int*)d_in[1];
  const int* target     = (const int*)d_in[2];
  const float* Wf  = (const float*)d_in[3];
  const float* bf_ = (const float*)d_in[4];
  const float* Wu  = (const float*)d_in[5];
  const float* bu  = (const float*)d_in[6];
  const float* w_cf = (const float*)d_in[7];
  const float* w_fc = (const float*)d_in[8];
  const float* w_ef = (const float*)d_in[9];
  const float* w_fe = (const float*)d_in[10];
  const float* b_c  = (const float*)d_in[11];
  const float* b_e  = (const float*)d_in[12];
  const float* head_tab = (const float*)d_in[13];
  const float* ent_tab  = (const float*)d_in[14];
  const float* W0 = (const float*)d_in[15];
  const float* b0 = (const float*)d_in[16];
  const float* W1 = (const float*)d_in[17];
  const float* b1 = (const float*)d_in[18];
  const float* W2 = (const float*)d_in[19];
  const float* b2 = (const float*)d_in[20];
  float* out = (float*)d_out;

  unsigned short* ws = (unsigned short*)d_ws;
  size_t off = 0;
  auto alloc = [&](size_t n) { unsigned short* p = ws + off; off += n; return p; };
  unsigned short* wfT  = alloc(32768);
  unsigned short* wuT  = alloc(16384);
  unsigned short* w0T  = alloc(131072);
  unsigned short* w1T  = alloc(131072);
  unsigned short* w2T  = alloc(2048);
  (void)ws_size; (void)in_sizes; (void)n_in; (void)out_size;

  // K1: weight transposes only
  prep_kernel<<<305, 256, 0, stream>>>(Wf, Wu, W0, W1, W2,
                                       wfT, wuT, w0T, w1T, w2T);
  // K2: full fused per-row pipeline, BK=128 mega-steps, 160KB LDS
  fused_mlp_kernel<<<256, 512, 0, stream>>>(features, ent_idx, head_tab,
      ent_tab, w_cf, w_fc, w_ef, w_fe, b_c, b_e, wfT, wuT, bf_, bu,
      w0T, b0, w1T, b1, w2T, b2, target, out);
}

// Round 9
// 179.506 us; speedup vs baseline: 1.0153x; 1.0153x over previous
//
#include <hip/hip_runtime.h>
#include <hip/hip_bf16.h>

// CompanyOperationEvaluation R18: cut LDS instruction count.
//  R17 post-mortem: step-halving null -> floor is TOTAL LDS instrs
//  (~320 ds_read_b128/wave + 144 scalar epilogue writes/wave ~= 18us).
//  Levers:
//   1. Wide waves for x0/x1: 32r x 64c per wave (acc[2][4]), stage tiles
//      256n x 64k (32KB) -> A re-reads across n-passes halve (x0/x1:
//      128 -> 96 reads/thread each).
//   2. Swapped-operand MFMA everywhere: mfma(b,a,acc) -> D-frag transposed,
//      lane holds 4 CONSECUTIVE COLS of one row -> epilogue = 1 uint2 write
//      per (mi,ni) instead of 4 scalar u16 (144 -> ~36 write instrs/wave).
//      LDS layouts unchanged (row-major + XOR swizzle); only lane->element
//      assignment changes. Operand frags are lane-symmetric so swap is free.
//  Schedule/staging/swizzle carried from R16/R17 verbatim: 3-buf b_sh,
//  counted vmcnt(4), gld_lds width-16 with inverse-swizzled source.
//  256 blocks x 512 thr x 64 rows, LDS 163840B, 1 block/CU.
// Lesson bank: (R2/R14) MFMA operands from LDS; (R5) >=8 MFMAs/wave/step;
// (R6) gather issue-early; (R13) block shape at const TLP neutral; (R15)
// swizzle alone neutral; (R16) counted vmcnt +8%; (R17) step count neutral
// at const LDS traffic -> LDS instr count is the lever this round tests.

typedef __bf16 bf16x8 __attribute__((ext_vector_type(8)));
typedef float floatx4 __attribute__((ext_vector_type(4)));

__device__ __forceinline__ unsigned short f2bf(float x) {
  unsigned int u = __builtin_bit_cast(unsigned int, x);
  u = (u + 0x7FFFu + ((u >> 16) & 1u)) >> 16;
  return (unsigned short)u;
}

__device__ __forceinline__ unsigned pack2(float a, float b) {
  return (unsigned)f2bf(a) | ((unsigned)f2bf(b) << 16);
}

// chunk-XOR swizzle: col in shorts; XORs 16B-chunk index low bits by row&7.
__device__ __forceinline__ int sz(int row, int col) {
  return col ^ ((row & 7) << 3);
}

#define BAR_VM(N)                                                      \
  do {                                                                 \
    asm volatile("s_waitcnt vmcnt(" #N ") lgkmcnt(0)" ::: "memory");   \
    __builtin_amdgcn_s_barrier();                                      \
    __builtin_amdgcn_sched_barrier(0);                                 \
  } while (0)

// ---------------------------------------------------------------------------
// K1 prep: blocks [0,304) 32x32 transpose tiles; block 304 W2.
// ---------------------------------------------------------------------------
__global__ __launch_bounds__(256) void prep_kernel(
    const float* __restrict__ Wf, const float* __restrict__ Wu,
    const float* __restrict__ W0, const float* __restrict__ W1,
    const float* __restrict__ W2,
    unsigned short* __restrict__ wfT, unsigned short* __restrict__ wuT,
    unsigned short* __restrict__ w0T, unsigned short* __restrict__ w1T,
    unsigned short* __restrict__ w2T) {
  __shared__ unsigned short tile[32][34];
  const int bid = blockIdx.x, tid = threadIdx.x;
  if (bid < 304) {
    int t = bid;
    const float* src; unsigned short* dst; int N, K, kt, nt;
    if (t < 32)       { src = Wf; dst = wfT; N = 128; K = 256; kt = t >> 2;       nt = t & 3; }
    else if (t < 48)  { t -= 32;  src = Wu; dst = wuT; N = 128; K = 128; kt = t >> 2; nt = t & 3; }
    else if (t < 176) { t -= 48;  src = W0; dst = w0T; N = 512; K = 256; kt = t >> 4; nt = t & 15; }
    else              { t -= 176; src = W1; dst = w1T; N = 256; K = 512; kt = t >> 3; nt = t & 7; }
    {
      int r = tid >> 3, cg = (tid & 7) * 4;
      float4 v = *(const float4*)(src + (size_t)(kt * 32 + r) * N + nt * 32 + cg);
      tile[r][cg + 0] = f2bf(v.x); tile[r][cg + 1] = f2bf(v.y);
      tile[r][cg + 2] = f2bf(v.z); tile[r][cg + 3] = f2bf(v.w);
    }
    __syncthreads();
    {
      int rp = tid >> 3, cg = (tid & 7) * 4;
      uint2 o;
      o.x = (unsigned)tile[cg + 0][rp] | ((unsigned)tile[cg + 1][rp] << 16);
      o.y = (unsigned)tile[cg + 2][rp] | ((unsigned)tile[cg + 3][rp] << 16);
      *(uint2*)(dst + (size_t)(nt * 32 + rp) * K + kt * 32 + cg) = o;
    }
  } else {
#pragma unroll
    for (int i = 0; i < 8; ++i) {
      int g = tid * 8 + i, k = g >> 3, n = g & 7;
      w2T[n * 256 + k] = f2bf(W2[g]);
    }
  }
}

// ---------------------------------------------------------------------------
// Staging: one 32KB B step-tile via global_load_lds width=16 (2048 chunks,
// 4 instr/thread). CPR = chunks per row (8: 256rx64k, 16: 128rx128k).
// LDS dest linear; global source inverse-swizzled (rule #21 both-sides).
// ---------------------------------------------------------------------------
template <int CPR, int LDK>
__device__ __forceinline__ void stageB(unsigned short* dstbase,
                                       const unsigned short* __restrict__ src,
                                       int tid) {
#pragma unroll
  for (int i = 0; i < 4; ++i) {
    int chunk = i * 512 + tid;
    int row = chunk / CPR, seg = chunk % CPR;
    int segl = seg ^ (row & 7);
    const unsigned short* g = src + (size_t)row * LDK + segl * 8;
    unsigned short* d = dstbase + chunk * 8;
    __builtin_amdgcn_global_load_lds((const unsigned int*)g, (unsigned int*)d,
                                     16, 0, 0);
  }
}

template <int PASS, int BK, int NROWS, int LDK>
__device__ __forceinline__ const unsigned short* srcstep(
    const unsigned short* __restrict__ s, int st) {
  return s + (size_t)(st / PASS) * NROWS * LDK + (st % PASS) * BK;
}

// Narrow K-step (BK=128, tile 128n x 128k): wave 32r x 32c, acc[4]=[mi*2+ni].
// SWAPPED mfma(b,a): D-frag lane&15 = A-row, quad*4+r = B-col.
template <int LDA>
__device__ __forceinline__ void mstep_n(const unsigned short* A,
                                        const unsigned short* bt, int k0,
                                        floatx4* acc, int m16, int quad,
                                        int wm, int wn) {
#pragma unroll
  for (int kk = 0; kk < 128; kk += 32) {
    const int ca = k0 + kk + quad * 8;
    const int cb = kk + quad * 8;
    const int ra0 = wm * 32 + m16, ra1 = wm * 32 + 16 + m16;
    const int rb0 = wn * 32 + m16, rb1 = wn * 32 + 16 + m16;
    bf16x8 a0 = *(const bf16x8*)&A[ra0 * LDA + sz(ra0, ca)];
    bf16x8 a1 = *(const bf16x8*)&A[ra1 * LDA + sz(ra1, ca)];
    bf16x8 b0 = *(const bf16x8*)&bt[rb0 * 128 + sz(rb0, cb)];
    bf16x8 b1 = *(const bf16x8*)&bt[rb1 * 128 + sz(rb1, cb)];
    acc[0] = __builtin_amdgcn_mfma_f32_16x16x32_bf16(b0, a0, acc[0], 0, 0, 0);
    acc[1] = __builtin_amdgcn_mfma_f32_16x16x32_bf16(b1, a0, acc[1], 0, 0, 0);
    acc[2] = __builtin_amdgcn_mfma_f32_16x16x32_bf16(b0, a1, acc[2], 0, 0, 0);
    acc[3] = __builtin_amdgcn_mfma_f32_16x16x32_bf16(b1, a1, acc[3], 0, 0, 0);
  }
}

// Wide K-step (BK=64, tile 256n x 64k): wave 32r x 64c, acc[8]=[mi*4+ni].
template <int LDA>
__device__ __forceinline__ void mstep_w(const unsigned short* A,
                                        const unsigned short* bt, int k0,
                                        floatx4* acc, int m16, int quad,
                                        int wm, int wn) {
#pragma unroll
  for (int kk = 0; kk < 64; kk += 32) {
    const int ca = k0 + kk + quad * 8;
    const int cb = kk + quad * 8;
    const int ra0 = wm * 32 + m16, ra1 = wm * 32 + 16 + m16;
    bf16x8 a0 = *(const bf16x8*)&A[ra0 * LDA + sz(ra0, ca)];
    bf16x8 a1 = *(const bf16x8*)&A[ra1 * LDA + sz(ra1, ca)];
    bf16x8 b[4];
#pragma unroll
    for (int ni = 0; ni < 4; ++ni) {
      int rb = wn * 64 + ni * 16 + m16;
      b[ni] = *(const bf16x8*)&bt[rb * 64 + sz(rb, cb)];
    }
#pragma unroll
    for (int ni = 0; ni < 4; ++ni) {
      acc[ni] = __builtin_amdgcn_mfma_f32_16x16x32_bf16(b[ni], a0, acc[ni], 0, 0, 0);
      acc[4 + ni] = __builtin_amdgcn_mfma_f32_16x16x32_bf16(b[ni], a1, acc[4 + ni], 0, 0, 0);
    }
  }
}

// Pipelined phases, 3-buf, lookahead-2, counted vmcnt (R16 schedule).
template <int T, int LDA, int PASS, int LDK>
__device__ __forceinline__ void gemm_phase_n(
    const unsigned short* A, const unsigned short* __restrict__ src,
    unsigned short* b_sh, floatx4* acc, int tid, int m16, int quad, int wm,
    int wn) {
  stageB<16, LDK>(b_sh, srcstep<PASS, 128, 128, LDK>(src, 0), tid);
  if (T > 1) {
    stageB<16, LDK>(b_sh + 16384, srcstep<PASS, 128, 128, LDK>(src, 1), tid);
    BAR_VM(4);
  } else {
    BAR_VM(0);
  }
#pragma unroll
  for (int t = 0; t < T; ++t) {
    if (t + 2 < T)
      stageB<16, LDK>(b_sh + ((t + 2) % 3) * 16384,
                      srcstep<PASS, 128, 128, LDK>(src, t + 2), tid);
    mstep_n<LDA>(A, b_sh + (t % 3) * 16384, (t % PASS) * 128,
                 acc + (t / PASS) * 4, m16, quad, wm, wn);
    if (t + 2 < T) {
      BAR_VM(4);
    } else {
      BAR_VM(0);
    }
  }
}

template <int T, int LDA, int PASS, int LDK>
__device__ __forceinline__ void gemm_phase_w(
    const unsigned short* A, const unsigned short* __restrict__ src,
    unsigned short* b_sh, floatx4* acc, int tid, int m16, int quad, int wm,
    int wn) {
  stageB<8, LDK>(b_sh, srcstep<PASS, 64, 256, LDK>(src, 0), tid);
  if (T > 1) {
    stageB<8, LDK>(b_sh + 16384, srcstep<PASS, 64, 256, LDK>(src, 1), tid);
    BAR_VM(4);
  } else {
    BAR_VM(0);
  }
#pragma unroll
  for (int t = 0; t < T; ++t) {
    if (t + 2 < T)
      stageB<8, LDK>(b_sh + ((t + 2) % 3) * 16384,
                     srcstep<PASS, 64, 256, LDK>(src, t + 2), tid);
    mstep_w<LDA>(A, b_sh + (t % 3) * 16384, (t % PASS) * 64,
                 acc + (t / PASS) * 8, m16, quad, wm, wn);
    if (t + 2 < T) {
      BAR_VM(4);
    } else {
      BAR_VM(0);
    }
  }
}

// ---------------------------------------------------------------------------
// K2 fused_mlp: 256 blocks x 64 rows x 512 threads. LDS = 163840 B exactly.
// ---------------------------------------------------------------------------
__global__ __launch_bounds__(512, 2) void fused_mlp_kernel(
    const float* __restrict__ features, const int* __restrict__ ent_idx,
    const float* __restrict__ head_tab, const float* __restrict__ ent_tab,
    const float* __restrict__ w_cf, const float* __restrict__ w_fc,
    const float* __restrict__ w_ef, const float* __restrict__ w_fe,
    const float* __restrict__ b_c, const float* __restrict__ b_e,
    const unsigned short* __restrict__ wfT,
    const unsigned short* __restrict__ wuT, const float* __restrict__ bf_,
    const float* __restrict__ bu,
    const unsigned short* __restrict__ w0T, const float* __restrict__ b0,
    const unsigned short* __restrict__ w1T, const float* __restrict__ b1,
    const unsigned short* __restrict__ w2T, const float* __restrict__ b2,
    const int* __restrict__ target, float* __restrict__ out) {
  // regionA (shorts): [0,16384) feat/A_sh 64x256; [16384,24576) buf0 64x128;
  // [24576,32768) buf1 64x128. x0_sh 64x512 = 32768 aliases all of regionA.
  __shared__ __align__(16) unsigned short regionA[32768];    // 64 KB
  __shared__ __align__(16) unsigned short b_sh[3 * 16384];   // 96 KB
  unsigned short* feat_sh = regionA;
  unsigned short* buf0 = regionA + 16384;
  unsigned short* buf1 = regionA + 24576;
  unsigned short* A_sh = regionA;   // 64x256: [cf2 | e] concat (swizzled)
  unsigned short* x0_sh = regionA;  // 64x512 (swizzled)
  unsigned short* x1_sh = b_sh;     // 64x264 = 16896 shorts (UNswizzled)

  const int tid = threadIdx.x;
  const int r0 = blockIdx.x * 64;
  const int lane = tid & 63, wave = tid >> 6;
  const int m16 = lane & 15, quad = lane >> 4;
  const int wm = wave >> 2, wn = wave & 3;   // narrow: 2m x 4n (32c)
  const int wn2 = wave & 1;                  // unused placeholder
  (void)wn2;

  // ---- gather issue (earliest point; consumed after L1) ----
  const int grow = tid >> 3, gpart = tid & 7;
  const int gidx = ent_idx[r0 + grow];
  const float* hp = head_tab + (size_t)gidx * 128 + gpart * 16;
  const float* ep = ent_tab + (size_t)gidx * 128 + gpart * 16;
  float4 h4[4], e4[4];
#pragma unroll
  for (int j = 0; j < 4; ++j) {
    h4[j] = *(const float4*)(hp + j * 4);
    e4[j] = *(const float4*)(ep + j * 4);
  }

  // stage features fp32->bf16 (swizzled uint4 writes): 2048 chunks, 4/thread
#pragma unroll
  for (int i = 0; i < 4; ++i) {
    int chunk = i * 512 + tid;
    int row = chunk >> 5, c8 = (chunk & 31) * 8;
    float4 v0 = *(const float4*)(features + (size_t)(r0 + row) * 256 + c8);
    float4 v1 = *(const float4*)(features + (size_t)(r0 + row) * 256 + c8 + 4);
    uint4 o;
    o.x = pack2(v0.x, v0.y); o.y = pack2(v0.z, v0.w);
    o.z = pack2(v1.x, v1.y); o.w = pack2(v1.z, v1.w);
    *(uint4*)&feat_sh[row * 256 + sz(row, c8)] = o;
  }

  floatx4 acc[4];
  // ---- L1: cf0 = relu(feat @ Wf + bf), K=256, N=128, T=2 (BK=128) ----
#pragma unroll
  for (int j = 0; j < 4; ++j) acc[j] = (floatx4){0.f, 0.f, 0.f, 0.f};
  gemm_phase_n<2, 256, 2, 256>(feat_sh, wfT, b_sh, acc, tid, m16, quad, wm, wn);
  // swapped-frag epilogue: row = ...+m16, 4 consecutive cols = ...+quad*4+r
#pragma unroll
  for (int mi = 0; mi < 2; ++mi)
#pragma unroll
    for (int ni = 0; ni < 2; ++ni) {
      int row = wm * 32 + mi * 16 + m16;
      int col = wn * 32 + ni * 16 + quad * 4;
      float4 bv = *(const float4*)(bf_ + col);
      floatx4 v = acc[mi * 2 + ni];
      uint2 o;
      o.x = pack2(fmaxf(v[0] + bv.x, 0.f), fmaxf(v[1] + bv.y, 0.f));
      o.y = pack2(fmaxf(v[2] + bv.z, 0.f), fmaxf(v[3] + bv.w, 0.f));
      *(uint2*)&buf0[row * 128 + sz(row, col)] = o;
    }

  // ---- cross_compress x2 (consume gather) -> A_sh[:,128:256] ----
  {
    float h[16], e[16];
#pragma unroll
    for (int j = 0; j < 4; ++j) {
      h[4 * j + 0] = h4[j].x; h[4 * j + 1] = h4[j].y;
      h[4 * j + 2] = h4[j].z; h[4 * j + 3] = h4[j].w;
      e[4 * j + 0] = e4[j].x; e[4 * j + 1] = e4[j].y;
      e[4 * j + 2] = e4[j].z; e[4 * j + 3] = e4[j].w;
    }
    float wcf[16], wfc[16], wef[16], wfe[16];
#pragma unroll
    for (int jj = 0; jj < 4; ++jj) {
      *(float4*)&wcf[jj * 4] = *(const float4*)(w_cf + gpart * 16 + jj * 4);
      *(float4*)&wfc[jj * 4] = *(const float4*)(w_fc + gpart * 16 + jj * 4);
      *(float4*)&wef[jj * 4] = *(const float4*)(w_ef + gpart * 16 + jj * 4);
      *(float4*)&wfe[jj * 4] = *(const float4*)(w_fe + gpart * 16 + jj * 4);
    }
    const float bc = b_c[0], be = b_e[0];
#pragma unroll
    for (int it = 0; it < 2; ++it) {
      float d0 = 0.f, d1 = 0.f, d2 = 0.f, d3 = 0.f;
#pragma unroll
      for (int j = 0; j < 16; ++j) {
        d0 += e[j] * wcf[j]; d1 += h[j] * wfc[j];
        d2 += e[j] * wef[j]; d3 += h[j] * wfe[j];
      }
#pragma unroll
      for (int s = 1; s < 8; s <<= 1) {
        d0 += __shfl_xor(d0, s); d1 += __shfl_xor(d1, s);
        d2 += __shfl_xor(d2, s); d3 += __shfl_xor(d3, s);
      }
#pragma unroll
      for (int j = 0; j < 16; ++j) {
        float nh = h[j] * d0 + e[j] * d1 + bc;
        float ne = h[j] * d2 + e[j] * d3 + be;
        h[j] = nh; e[j] = ne;
      }
    }
    uint4 o0, o1;
    unsigned* w = (unsigned*)&o0;
#pragma unroll
    for (int j = 0; j < 4; ++j) w[j] = pack2(e[2 * j], e[2 * j + 1]);
    w = (unsigned*)&o1;
#pragma unroll
    for (int j = 0; j < 4; ++j) w[j] = pack2(e[8 + 2 * j], e[8 + 2 * j + 1]);
    const int c0 = 128 + gpart * 16;
    *(uint4*)&A_sh[grow * 256 + sz(grow, c0)] = o0;
    *(uint4*)&A_sh[grow * 256 + sz(grow, c0 + 8)] = o1;
  }

  // ---- L2: cf1 = relu(cf0 @ Wu + bu), K=128, N=128, T=1 ----
#pragma unroll
  for (int j = 0; j < 4; ++j) acc[j] = (floatx4){0.f, 0.f, 0.f, 0.f};
  gemm_phase_n<1, 128, 1, 128>(buf0, wuT, b_sh, acc, tid, m16, quad, wm, wn);
#pragma unroll
  for (int mi = 0; mi < 2; ++mi)
#pragma unroll
    for (int ni = 0; ni < 2; ++ni) {
      int row = wm * 32 + mi * 16 + m16;
      int col = wn * 32 + ni * 16 + quad * 4;
      float4 bv = *(const float4*)(bu + col);
      floatx4 v = acc[mi * 2 + ni];
      uint2 o;
      o.x = pack2(fmaxf(v[0] + bv.x, 0.f), fmaxf(v[1] + bv.y, 0.f));
      o.y = pack2(fmaxf(v[2] + bv.z, 0.f), fmaxf(v[3] + bv.w, 0.f));
      *(uint2*)&buf1[row * 128 + sz(row, col)] = o;
    }

  // ---- L3: cf2 = relu(cf1 @ Wu + bu) -> A_sh[:,0:128] ----
  // b_sh[0] still holds the full wuT tile from L2: zero staging.
#pragma unroll
  for (int j = 0; j < 4; ++j) acc[j] = (floatx4){0.f, 0.f, 0.f, 0.f};
  BAR_VM(0);  // buf1 (L2 epilogue ds_writes) visible to all waves
  mstep_n<128>(buf1, b_sh, 0, acc, m16, quad, wm, wn);
  BAR_VM(0);  // drain b_sh reads before x0's stage(0) overwrites b_sh
#pragma unroll
  for (int mi = 0; mi < 2; ++mi)
#pragma unroll
    for (int ni = 0; ni < 2; ++ni) {
      int row = wm * 32 + mi * 16 + m16;
      int col = wn * 32 + ni * 16 + quad * 4;
      float4 bv = *(const float4*)(bu + col);
      floatx4 v = acc[mi * 2 + ni];
      uint2 o;
      o.x = pack2(fmaxf(v[0] + bv.x, 0.f), fmaxf(v[1] + bv.y, 0.f));
      o.y = pack2(fmaxf(v[2] + bv.z, 0.f), fmaxf(v[3] + bv.w, 0.f));
      *(uint2*)&A_sh[row * 256 + sz(row, col)] = o;
    }

  // ---- x0 = relu(A @ W0 + b0), K=256, N=512: wide, 2 np x 4 k = T=8 ----
  floatx4 acc16[16];
#pragma unroll
  for (int j = 0; j < 16; ++j) acc16[j] = (floatx4){0.f, 0.f, 0.f, 0.f};
  gemm_phase_w<8, 256, 4, 256>(A_sh, w0T, b_sh, acc16, tid, m16, quad, wm, wn);
  // epilogue -> x0_sh (overwrites regionA; all A reads drained at final bar)
#pragma unroll
  for (int np = 0; np < 2; ++np)
#pragma unroll
    for (int mi = 0; mi < 2; ++mi)
#pragma unroll
      for (int ni = 0; ni < 4; ++ni) {
        int row = wm * 32 + mi * 16 + m16;
        int col = np * 256 + wn * 64 + ni * 16 + quad * 4;
        float4 bv = *(const float4*)(b0 + col);
        floatx4 v = acc16[np * 8 + mi * 4 + ni];
        uint2 o;
        o.x = pack2(fmaxf(v[0] + bv.x, 0.f), fmaxf(v[1] + bv.y, 0.f));
        o.y = pack2(fmaxf(v[2] + bv.z, 0.f), fmaxf(v[3] + bv.w, 0.f));
        *(uint2*)&x0_sh[row * 512 + sz(row, col)] = o;
      }

  // ---- x1 = relu(x0 @ W1 + b1), K=512, N=256: wide, 1 np x 8 k = T=8 ----
  floatx4 acc8[8];
#pragma unroll
  for (int j = 0; j < 8; ++j) acc8[j] = (floatx4){0.f, 0.f, 0.f, 0.f};
  gemm_phase_w<8, 512, 8, 512>(x0_sh, w1T, b_sh, acc8, tid, m16, quad, wm, wn);
  // epilogue -> x1_sh aliased over b_sh (all b_sh reads drained at final bar)
#pragma unroll
  for (int mi = 0; mi < 2; ++mi)
#pragma unroll
    for (int ni = 0; ni < 4; ++ni) {
      int row = wm * 32 + mi * 16 + m16;
      int col = wn * 64 + ni * 16 + quad * 4;
      float4 bv = *(const float4*)(b1 + col);
      floatx4 v = acc8[mi * 4 + ni];
      uint2 o;
      o.x = pack2(fmaxf(v[0] + bv.x, 0.f), fmaxf(v[1] + bv.y, 0.f));
      o.y = pack2(fmaxf(v[2] + bv.z, 0.f), fmaxf(v[3] + bv.w, 0.f));
      *(uint2*)&x1_sh[row * 264 + col] = o;
    }
  BAR_VM(0);

  // W2 GEMV + softmax: 8 lanes/row, 64 rows; w2T direct from global
  // (4KB, L2-hot, tail phase only).
  {
    int row = tid >> 3, q = tid & 7;
    float p[8];
#pragma unroll
    for (int n = 0; n < 8; ++n) p[n] = 0.f;
#pragma unroll
    for (int jb = 0; jb < 4; ++jb) {
      bf16x8 xv = *(const bf16x8*)&x1_sh[row * 264 + q * 32 + jb * 8];
#pragma unroll
      for (int n = 0; n < 8; ++n) {
        bf16x8 wv = *(const bf16x8*)(w2T + n * 256 + q * 32 + jb * 8);
#pragma unroll
        for (int j = 0; j < 8; ++j) p[n] += (float)xv[j] * (float)wv[j];
      }
    }
#pragma unroll
    for (int s = 1; s < 8; s <<= 1)
#pragma unroll
      for (int n = 0; n < 8; ++n) p[n] += __shfl_xor(p[n], s);
    if (q == 0) {
      float mx = -1e30f;
#pragma unroll
      for (int n = 0; n < 8; ++n) {
        p[n] = fmaxf(p[n] + b2[n], 0.f);
        mx = fmaxf(mx, p[n]);
      }
      float sum = 0.f;
#pragma unroll
      for (int n = 0; n < 8; ++n) { p[n] = __expf(p[n] - mx); sum += p[n]; }
      const float inv = 1.f / sum;
      const int gr = r0 + row;
      float4 o0 = {p[0] * inv, p[1] * inv, p[2] * inv, p[3] * inv};
      float4 o1 = {p[4] * inv, p[5] * inv, p[6] * inv, p[7] * inv};
      *(float4*)(out + (size_t)gr * 8) = o0;
      *(float4*)(out + (size_t)gr * 8 + 4) = o1;
      out[16384 * 8 + gr] = (float)target[gr];
    }
  }
}

extern "C" void kernel_launch(void* const* d_in, const int* in_sizes, int n_in,
                              void* d_out, int out_size, void* d_ws, size_t ws_size,
                              hipStream_t stream) {
  const float* features = (const float*)d_in[0];
  const int* ent_idx    = (const int*)d_in[1];
  const int* target     = (const int*)d_in[2];
  const float* Wf  = (const float*)d_in[3];
  const float* bf_ = (const float*)d_in[4];
  const float* Wu  = (const float*)d_in[5];
  const float* bu  = (const float*)d_in[6];
  const float* w_cf = (const float*)d_in[7];
  const float* w_fc = (const float*)d_in[8];
  const float* w_ef = (const float*)d_in[9];
  const float* w_fe = (const float*)d_in[10];
  const float* b_c  = (const float*)d_in[11];
  const float* b_e  = (const float*)d_in[12];
  const float* head_tab = (const float*)d_in[13];
  const float* ent_tab  = (const float*)d_in[14];
  const float* W0 = (const float*)d_in[15];
  const float* b0 = (const float*)d_in[16];
  const float* W1 = (const float*)d_in[17];
  const float* b1 = (const float*)d_in[18];
  const float* W2 = (const float*)d_in[19];
  const float* b2 = (const float*)d_in[20];
  float* out = (float*)d_out;

  unsigned short* ws = (unsigned short*)d_ws;
  size_t off = 0;
  auto alloc = [&](size_t n) { unsigned short* p = ws + off; off += n; return p; };
  unsigned short* wfT  = alloc(32768);
  unsigned short* wuT  = alloc(16384);
  unsigned short* w0T  = alloc(131072);
  unsigned short* w1T  = alloc(131072);
  unsigned short* w2T  = alloc(2048);
  (void)ws_size; (void)in_sizes; (void)n_in; (void)out_size;

  // K1: weight transposes only
  prep_kernel<<<305, 256, 0, stream>>>(Wf, Wu, W0, W1, W2,
                                       wfT, wuT, w0T, w1T, w2T);
  // K2: full fused per-row pipeline, wide x0/x1 waves + vectorized epilogues
  fused_mlp_kernel<<<256, 512, 0, stream>>>(features, ent_idx, head_tab,
      ent_tab, w_cf, w_fc, w_ef, w_fe, b_c, b_e, wfT, wuT, bf_, bu,
      w0T, b0, w1T, b1, w2T, b2, target, out);
}